// Round 8
// baseline (239.168 us; speedup 1.0000x reference)
//
#include <hip/hip_runtime.h>
#include <hip/hip_bf16.h>
#include <math.h>

#define BDIM 2
#define NDIM 512
#define HID 768
#define BIAF 256
#define CLS 14
#define DD 257   // BIAF+1
#define NPOS 30
#define SDIM 25
#define HSZ 539  // 2*257+25
#define PK 288   // padded contraction length (i and j), 9*32
#define PJ 384   // packW j-rows padding
#define NCH 9    // K chunks of 32 in PK

typedef unsigned short ushort_t;
typedef __attribute__((ext_vector_type(8))) short short8;   // 8 bf16
typedef __attribute__((ext_vector_type(4))) float floatx4;  // 4 f32

#define MFMA16(a, b, c) __builtin_amdgcn_mfma_f32_16x16x32_bf16((a), (b), (c), 0, 0, 0)

__device__ inline float bf2f(ushort_t u) {
    union { unsigned int i; float f; } c; c.i = ((unsigned)u) << 16; return c.f;
}
__device__ inline ushort_t f2bf(float f) {
    __hip_bfloat16 h = __float2bfloat16(f);
    return *(ushort_t*)&h;
}

// ---------------------------------------------------------------------------
// prep: fused preprocessing.
//   blocks [0,1512)        : packW[k][j][i] = bf16(biafW[k][i][j]) zero-padded
//   blocks [1512,4584)     : wsplit (4 proj weight mats -> hi/lo planes)
//   blocks [4584,10728)    : xysplit (x,y -> hi/lo planes)
//   blocks [10728,11240)   : fill pad cols of h1/t1 planes
// ---------------------------------------------------------------------------
__global__ __launch_bounds__(256) void prep(
    const float* __restrict__ biafW,
    const float* __restrict__ m1w, const float* __restrict__ m2w,
    const float* __restrict__ hw,  const float* __restrict__ tw,
    const float* __restrict__ x,   const float* __restrict__ y,
    ushort_t* __restrict__ packW,
    ushort_t* __restrict__ whi, ushort_t* __restrict__ wlo,
    ushort_t* __restrict__ xhi, ushort_t* __restrict__ xlo,
    ushort_t* __restrict__ yhi, ushort_t* __restrict__ ylo,
    ushort_t* __restrict__ h1hi, ushort_t* __restrict__ h1lo,
    ushort_t* __restrict__ t1hi, ushort_t* __restrict__ t1lo)
{
    __shared__ float tile[32][33];
    const int bx = blockIdx.x;
    const int tid = threadIdx.x;
    if (bx < 1512) {
        int k = bx / 108, rem = bx % 108;
        int i0 = (rem / 12) * 32, j0 = (rem % 12) * 32;
        int r8 = tid >> 5, c = tid & 31;
        #pragma unroll
        for (int rr = 0; rr < 4; ++rr) {
            int r = rr * 8 + r8;
            int gi = i0 + r, gj = j0 + c;
            tile[r][c] = (gi < DD && gj < DD) ? biafW[((size_t)k * DD + gi) * DD + gj] : 0.f;
        }
        __syncthreads();
        #pragma unroll
        for (int rr = 0; rr < 4; ++rr) {
            int jr = rr * 8 + r8;
            packW[((size_t)k * PJ + (j0 + jr)) * PK + i0 + c] = f2bf(tile[c][jr]);
        }
    } else if (bx < 4584) {
        int idx = (bx - 1512) * 256 + tid;               // 786432
        int mat = idx / (BIAF * HID);
        int rem = idx % (BIAF * HID);
        const float* src = (mat == 0) ? m1w : (mat == 1) ? m2w : (mat == 2) ? hw : tw;
        float v = src[rem];
        ushort_t h = f2bf(v);
        whi[idx] = h;
        wlo[idx] = f2bf(v - bf2f(h));
    } else if (bx < 10728) {
        int idx = (bx - 4584) * 256 + tid;               // 1572864
        int which = idx >= (BDIM * NDIM * HID);
        int rem = which ? idx - BDIM * NDIM * HID : idx;
        float v = (which ? y : x)[rem];
        ushort_t h = f2bf(v);
        (which ? yhi : xhi)[rem] = h;
        (which ? ylo : xlo)[rem] = f2bf(v - bf2f(h));
    } else {
        int idx = (bx - 10728) * 256 + tid;              // 131072
        int plane = idx >> 15;
        int tok = (idx >> 5) & 1023;
        int c = 256 + (idx & 31);
        ushort_t* dst = (plane == 0) ? h1hi : (plane == 1) ? h1lo : (plane == 2) ? t1hi : t1lo;
        ushort_t val = (c == 256 && (plane == 0 || plane == 2)) ? (ushort_t)0x3F80 : (ushort_t)0;
        dst[(size_t)tok * PK + c] = val;
    }
}

// ---------------------------------------------------------------------------
// proj v4: wave tile 16 tokens x 16 features, rotating register prefetch.
// grid (16 ft, 16 mt, 4 proj) = 1024 blocks.
// ---------------------------------------------------------------------------
__global__ __launch_bounds__(256, 4) void proj_mfma(
    const ushort_t* __restrict__ xhi, const ushort_t* __restrict__ xlo,
    const ushort_t* __restrict__ yhi, const ushort_t* __restrict__ ylo,
    const ushort_t* __restrict__ whi, const ushort_t* __restrict__ wlo,
    const float* __restrict__ m1b, const float* __restrict__ m2b,
    const float* __restrict__ hb,  const float* __restrict__ tb,
    ushort_t* __restrict__ h1hi, ushort_t* __restrict__ h1lo,
    ushort_t* __restrict__ t1hi, ushort_t* __restrict__ t1lo,
    float* __restrict__ headf, float* __restrict__ tailf)
{
    const int ft = blockIdx.x;       // 16 features
    const int mt = blockIdx.y;       // 64 tokens
    const int proj = blockIdx.z;
    const int wave = threadIdx.x >> 6, L = threadIdx.x & 63;
    const int quad = L >> 4, l16 = L & 15;
    const int tok0 = mt * 64 + wave * 16;
    const int f0 = ft * 16;

    const ushort_t* ah_p = (proj == 1) ? yhi : xhi;
    const ushort_t* al_p = (proj == 1) ? ylo : xlo;
    const float* bias = (proj == 0) ? m1b : (proj == 1) ? m2b : (proj == 2) ? hb : tb;

    const ushort_t* pa_h = ah_p + (size_t)(tok0 + l16) * HID + quad * 8;
    const ushort_t* pa_l = al_p + (size_t)(tok0 + l16) * HID + quad * 8;
    const size_t wb = (size_t)proj * BIAF * HID + (size_t)(f0 + l16) * HID + quad * 8;
    const ushort_t* pb_h = whi + wb;
    const ushort_t* pb_l = wlo + wb;

    floatx4 acc = {0.f, 0.f, 0.f, 0.f};
    short8 ah = *(const short8*)pa_h;
    short8 al = *(const short8*)pa_l;
    short8 bh = *(const short8*)pb_h;
    short8 bl = *(const short8*)pb_l;
    #pragma unroll
    for (int k0 = 32; k0 < HID; k0 += 32) {
        short8 ah2 = *(const short8*)(pa_h + k0);
        short8 al2 = *(const short8*)(pa_l + k0);
        short8 bh2 = *(const short8*)(pb_h + k0);
        short8 bl2 = *(const short8*)(pb_l + k0);
        acc = MFMA16(ah, bh, acc);
        acc = MFMA16(al, bh, acc);
        acc = MFMA16(ah, bl, acc);
        ah = ah2; al = al2; bh = bh2; bl = bl2;
    }
    acc = MFMA16(ah, bh, acc);
    acc = MFMA16(al, bh, acc);
    acc = MFMA16(ah, bl, acc);

    const int feat = f0 + l16;
    const float bv = bias[feat];
    #pragma unroll
    for (int r = 0; r < 4; ++r) {
        int tok = tok0 + quad * 4 + r;
        float v = acc[r] + bv;
        if (proj <= 1) {
            float g = 0.5f * v * (1.0f + erff(v * 0.70710678118654752f));
            ushort_t h = f2bf(g);
            ushort_t lo = f2bf(g - bf2f(h));
            if (proj == 0) { h1hi[(size_t)tok * PK + feat] = h; h1lo[(size_t)tok * PK + feat] = lo; }
            else           { t1hi[(size_t)tok * PK + feat] = h; t1lo[(size_t)tok * PK + feat] = lo; }
        } else {
            float lv = (v >= 0.f) ? v : 0.01f * v;
            if (proj == 2) headf[(size_t)tok * 256 + feat] = lv;
            else           tailf[(size_t)tok * 256 + feat] = lv;
        }
    }
}

// ---------------------------------------------------------------------------
// hktk_sk: blocks [0,128) compute hk/tk dots; blocks [128,130) compute sk.
// ---------------------------------------------------------------------------
__global__ __launch_bounds__(256) void hktk_sk(
    const float* __restrict__ headf, const float* __restrict__ tailf,
    const float* __restrict__ W, const float* __restrict__ semb,
    float* __restrict__ hk, float* __restrict__ tk, float* __restrict__ skp)
{
    const int bx = blockIdx.x;
    if (bx < 128) {
        int p = bx * 256 + threadIdx.x;
        int which = p >> 14;
        int idx = p & 16383;
        int tok = idx >> 4;
        int k = idx & 15;
        if (k >= CLS) return;
        const float* row = (which ? tailf : headf) + (size_t)tok * 256;
        const float* wr = W + (size_t)k * HSZ + (which ? DD : 0);
        float acc = 0.f;
        for (int f4 = 0; f4 < 64; ++f4) {
            float4 rv = *(const float4*)(row + f4 * 4);
            acc += rv.x * wr[f4*4] + rv.y * wr[f4*4+1] + rv.z * wr[f4*4+2] + rv.w * wr[f4*4+3];
        }
        acc += wr[256];
        float* dst = which ? tk : hk;
        dst[(size_t)(tok >> 9) * CLS * NDIM + (size_t)k * NDIM + (tok & 511)] = acc;
    } else {
        int idx = (bx - 128) * 256 + threadIdx.x;
        if (idx < CLS * NPOS) {
            int k = idx / NPOS, d = idx % NPOS;
            float acc = 0.f;
            for (int h = 0; h < SDIM; ++h)
                acc += semb[d*SDIM + h] * W[k*HSZ + 2*DD + h];
            skp[idx] = acc;
        }
    }
}

// ---------------------------------------------------------------------------
// mb v4: A[bk][m][j] = sum_i h1[m][i] * packW[k][j][i]  (2-term on h1)
// wave tile 16m x 48j, A fully preloaded in regs, B prefetched 1 chunk ahead.
// grid (6 jt, 8 mt, 28 bk) = 1344 blocks.
// ---------------------------------------------------------------------------
__global__ __launch_bounds__(256) void mb_tile(
    const ushort_t* __restrict__ h1hi, const ushort_t* __restrict__ h1lo,
    const ushort_t* __restrict__ packW,
    ushort_t* __restrict__ Ab)
{
    const int jt = blockIdx.x, mt = blockIdx.y, bk = blockIdx.z;
    const int b = bk / CLS, k = bk % CLS;
    const int wave = threadIdx.x >> 6, L = threadIdx.x & 63;
    const int quad = L >> 4, l16 = L & 15;
    const int m0 = mt * 64 + wave * 16;
    const int j0 = jt * 48;

    const size_t aoff = (size_t)(b * NDIM + m0 + l16) * PK + quad * 8;
    short8 ahi[NCH], alo[NCH];
    #pragma unroll
    for (int c = 0; c < NCH; ++c) {
        ahi[c] = *(const short8*)(h1hi + aoff + c * 32);
        alo[c] = *(const short8*)(h1lo + aoff + c * 32);
    }

    const ushort_t* pb[3];
    #pragma unroll
    for (int ni = 0; ni < 3; ++ni)
        pb[ni] = packW + ((size_t)k * PJ + j0 + ni * 16 + l16) * PK + quad * 8;

    floatx4 acc[3];
    #pragma unroll
    for (int ni = 0; ni < 3; ++ni)
        #pragma unroll
        for (int r = 0; r < 4; ++r) acc[ni][r] = 0.f;

    short8 bb[3], bn[3];
    #pragma unroll
    for (int ni = 0; ni < 3; ++ni) bb[ni] = *(const short8*)pb[ni];
    #pragma unroll
    for (int c = 0; c < NCH; ++c) {
        if (c + 1 < NCH) {
            #pragma unroll
            for (int ni = 0; ni < 3; ++ni) bn[ni] = *(const short8*)(pb[ni] + (c + 1) * 32);
        }
        #pragma unroll
        for (int ni = 0; ni < 3; ++ni) {
            acc[ni] = MFMA16(ahi[c], bb[ni], acc[ni]);
            acc[ni] = MFMA16(alo[c], bb[ni], acc[ni]);
        }
        if (c + 1 < NCH) {
            #pragma unroll
            for (int ni = 0; ni < 3; ++ni) bb[ni] = bn[ni];
        }
    }

    ushort_t* Aout = Ab + (size_t)bk * NDIM * PK;
    #pragma unroll
    for (int r = 0; r < 4; ++r) {
        int row = m0 + quad * 4 + r;
        #pragma unroll
        for (int ni = 0; ni < 3; ++ni) {
            int col = j0 + ni * 16 + l16;
            Aout[(size_t)row * PK + col] = f2bf(acc[ni][r]);
        }
    }
}

// ---------------------------------------------------------------------------
// mo v4: out[bk][m][n] = sum_j A[m][j] * t1[n][j] + hk + tk + sk  (2-term on t1)
// wave tile 16m x 64n, A fully preloaded in regs, B prefetched 1 chunk ahead.
// grid (8 nt, 8 mt, 28 bk) = 1792 blocks.
// ---------------------------------------------------------------------------
__global__ __launch_bounds__(256) void mo_tile(
    const ushort_t* __restrict__ Ab,
    const ushort_t* __restrict__ t1hi, const ushort_t* __restrict__ t1lo,
    const float* __restrict__ hk, const float* __restrict__ tk,
    const float* __restrict__ skp,
    float* __restrict__ out)
{
    __shared__ float skr[NPOS];
    const int nt = blockIdx.x, mt = blockIdx.y, bk = blockIdx.z;
    const int b = bk / CLS, k = bk % CLS;
    if (threadIdx.x < NPOS) skr[threadIdx.x] = skp[k * NPOS + threadIdx.x];
    __syncthreads();
    const int wave = threadIdx.x >> 6, L = threadIdx.x & 63;
    const int quad = L >> 4, l16 = L & 15;
    const int m0 = mt * 64 + wave * 16;
    const int n0 = nt * 64;

    const size_t aoff = ((size_t)bk * NDIM + m0 + l16) * PK + quad * 8;
    short8 a[NCH];
    #pragma unroll
    for (int c = 0; c < NCH; ++c) a[c] = *(const short8*)(Ab + aoff + c * 32);

    const ushort_t* pbh[4];
    const ushort_t* pbl[4];
    #pragma unroll
    for (int ni = 0; ni < 4; ++ni) {
        size_t boff = (size_t)(b * NDIM + n0 + ni * 16 + l16) * PK + quad * 8;
        pbh[ni] = t1hi + boff;
        pbl[ni] = t1lo + boff;
    }

    floatx4 acc[4];
    #pragma unroll
    for (int ni = 0; ni < 4; ++ni)
        #pragma unroll
        for (int r = 0; r < 4; ++r) acc[ni][r] = 0.f;

    short8 bh[4], bl[4], bh2[4], bl2[4];
    #pragma unroll
    for (int ni = 0; ni < 4; ++ni) {
        bh[ni] = *(const short8*)pbh[ni];
        bl[ni] = *(const short8*)pbl[ni];
    }
    #pragma unroll
    for (int c = 0; c < NCH; ++c) {
        if (c + 1 < NCH) {
            #pragma unroll
            for (int ni = 0; ni < 4; ++ni) {
                bh2[ni] = *(const short8*)(pbh[ni] + (c + 1) * 32);
                bl2[ni] = *(const short8*)(pbl[ni] + (c + 1) * 32);
            }
        }
        #pragma unroll
        for (int ni = 0; ni < 4; ++ni) {
            acc[ni] = MFMA16(a[c], bh[ni], acc[ni]);
            acc[ni] = MFMA16(a[c], bl[ni], acc[ni]);
        }
        if (c + 1 < NCH) {
            #pragma unroll
            for (int ni = 0; ni < 4; ++ni) { bh[ni] = bh2[ni]; bl[ni] = bl2[ni]; }
        }
    }

    const size_t obase = (size_t)bk * NDIM;
    #pragma unroll
    for (int r = 0; r < 4; ++r) {
        int row = m0 + quad * 4 + r;
        float hv = hk[obase + row];
        #pragma unroll
        for (int ni = 0; ni < 4; ++ni) {
            int col = n0 + ni * 16 + l16;
            int d = col - row; d = d < -15 ? -15 : (d > 14 ? 14 : d); d += 15;
            out[(obase + row) * NDIM + col] = acc[ni][r] + hv + tk[obase + col] + skr[d];
        }
    }
}

// ---------------------------------------------------------------------------
extern "C" void kernel_launch(void* const* d_in, const int* in_sizes, int n_in,
                              void* d_out, int out_size, void* d_ws, size_t ws_size,
                              hipStream_t stream) {
    const float* x    = (const float*)d_in[0];
    const float* y    = (const float*)d_in[1];
    // d_in[2] = z : unused
    const float* m1w  = (const float*)d_in[3];
    const float* m1b  = (const float*)d_in[4];
    const float* m2w  = (const float*)d_in[5];
    const float* m2b  = (const float*)d_in[6];
    const float* hw   = (const float*)d_in[7];
    const float* hb   = (const float*)d_in[8];
    const float* tw   = (const float*)d_in[9];
    const float* tb   = (const float*)d_in[10];
    const float* biafW= (const float*)d_in[11];
    const float* W    = (const float*)d_in[12];
    const float* semb = (const float*)d_in[13];

    char* p = (char*)d_ws;
    float* hk   = (float*)p;                    p += 57344;
    float* tk   = (float*)p;                    p += 57344;
    float* skp  = (float*)p;                    p += 2048;
    float* headf= (float*)p;                    p += 1048576;
    float* tailf= (float*)p;                    p += 1048576;
    ushort_t* h1hi = (ushort_t*)p;              p += 589824;
    ushort_t* h1lo = (ushort_t*)p;              p += 589824;
    ushort_t* t1hi = (ushort_t*)p;              p += 589824;
    ushort_t* t1lo = (ushort_t*)p;              p += 589824;
    ushort_t* packW= (ushort_t*)p;              p += 3096576;  // 14*384*288*2
    ushort_t* whi  = (ushort_t*)p;              p += 1572864;  // 4*256*768*2
    ushort_t* wlo  = (ushort_t*)p;              p += 1572864;
    ushort_t* Abuf = (ushort_t*)p;              p += 8257536;  // 28*512*288*2
    ushort_t* xhi  = (ushort_t*)p;              p += 1572864;  // 1024*768*2
    ushort_t* xlo  = (ushort_t*)p;              p += 1572864;
    ushort_t* yhi  = (ushort_t*)p;              p += 1572864;
    ushort_t* ylo  = (ushort_t*)p;              p += 1572864;

    prep<<<11240, 256, 0, stream>>>(biafW, m1w, m2w, hw, tw, x, y,
                                    packW, whi, wlo, xhi, xlo, yhi, ylo,
                                    h1hi, h1lo, t1hi, t1lo);
    proj_mfma<<<dim3(16, 16, 4), 256, 0, stream>>>(xhi, xlo, yhi, ylo, whi, wlo,
                                                   m1b, m2b, hb, tb,
                                                   h1hi, h1lo, t1hi, t1lo, headf, tailf);
    hktk_sk<<<130, 256, 0, stream>>>(headf, tailf, W, semb, hk, tk, skp);
    mb_tile<<<dim3(6, 8, BDIM*CLS), 256, 0, stream>>>(h1hi, h1lo, packW, Abuf);
    mo_tile<<<dim3(8, 8, BDIM*CLS), 256, 0, stream>>>(Abuf, t1hi, t1lo, hk, tk, skp,
                                                      (float*)d_out);
}